// Round 1
// baseline (4259.313 us; speedup 1.0000x reference)
//
#include <hip/hip_runtime.h>
#include <hip/hip_bf16.h>

// Problem constants
#define BB      16
#define CIN     768
#define HID     256
#define NH      37
#define NW      37
#define NPOS    1369      // 37*37
#define PADW    39
#define PPAD    1521      // 39*39
#define PP      14
#define KOUT    1764      // 9*14*14
#define HOUT    518
#define CONF_OFF ((size_t)BB*2*HOUT*HOUT)

// Workspace layout (floats)
//  xpad : BB*CIN*PPAD = 18,690,048
//  h1f  : BB*HID*PPAD =  6,230,016
//  h1w  : BB*HID*PPAD =  6,230,016
//  fpad : BB*3*PPAD   =     73,008
//  wt1f : 9*CIN*HID   =  1,769,472
//  wt1w : 9*CIN*HID   =  1,769,472
//  wt2  : HID*KOUT    =    451,584
// total 35,213,616 floats = ~134.3 MiB
static constexpr size_t OFF_XPAD = 0;
static constexpr size_t OFF_H1F  = OFF_XPAD + (size_t)BB*CIN*PPAD;
static constexpr size_t OFF_H1W  = OFF_H1F  + (size_t)BB*HID*PPAD;
static constexpr size_t OFF_FPAD = OFF_H1W  + (size_t)BB*HID*PPAD;
static constexpr size_t OFF_WT1F = OFF_FPAD + (size_t)BB*3*PPAD;
static constexpr size_t OFF_WT1W = OFF_WT1F + (size_t)9*CIN*HID;
static constexpr size_t OFF_WT2  = OFF_WT1W + (size_t)9*CIN*HID;
static constexpr size_t ACT_BYTES = OFF_WT1F * sizeof(float);   // zeroed region

// tokens[b][pos][c] -> xpad[b][c][1+h][1+w]  (LDS transpose tile 64pos x 32c)
__global__ void pack_tokens(const float* __restrict__ tok, float* __restrict__ xpad) {
    __shared__ float t[64][33];
    int bb   = blockIdx.z;
    int pos0 = blockIdx.x * 64;
    int c0   = blockIdx.y * 32;
    int tid  = threadIdx.x;
    #pragma unroll
    for (int i = 0; i < 8; ++i) {
        int e = tid + 256 * i;
        int p = e >> 5, c = e & 31;
        int pos = pos0 + p;
        float v = 0.f;
        if (pos < NPOS) v = tok[((size_t)bb * NPOS + pos) * CIN + c0 + c];
        t[p][c] = v;
    }
    __syncthreads();
    #pragma unroll
    for (int i = 0; i < 8; ++i) {
        int e = tid + 256 * i;
        int c = e >> 6, p = e & 63;
        int pos = pos0 + p;
        if (pos < NPOS) {
            int h = pos / NW, w = pos - (pos / NW) * NW;
            xpad[(((size_t)bb * CIN + c0 + c) * PADW + h + 1) * PADW + w + 1] = t[p][c];
        }
    }
}

// w[co][ci][kk] -> wt[kk][ci][co]
__global__ void transpose_w(const float* __restrict__ w, float* __restrict__ wt,
                            int Cout, int Cin, int KK) {
    int idx = blockIdx.x * 256 + threadIdx.x;
    int total = Cout * Cin * KK;
    if (idx >= total) return;
    int co = idx % Cout;
    int r  = idx / Cout;
    int ci = r % Cin;
    int kk = r / Cin;
    wt[idx] = w[((size_t)co * Cin + ci) * KK + kk];
}

// 3x3 SAME conv as implicit GEMM over 9 shifted taps.
// xpad[b][Cin][39][39] (zero border), wt[kk][ci][co], out ypad[b][Cout][39][39] interior.
template <bool RELU>
__global__ void conv3x3_fused(const float* __restrict__ xpad, const float* __restrict__ wt,
                              const float* __restrict__ bias, float* __restrict__ ypad,
                              int Cin, int Cout) {
    __shared__ float As[32][32];   // [ci][pos]
    __shared__ float Ws[32][64];   // [ci][co]
    int bb   = blockIdx.z;
    int pos0 = blockIdx.x * 32;
    int co0  = blockIdx.y * 64;
    int tid  = threadIdx.x;
    int tx   = tid & 7;    // pos quad: pos = tx*4+i
    int ty   = tid >> 3;   // 0..31 : co pair = ty*2+j
    float acc[2][4] = {{0.f,0.f,0.f,0.f},{0.f,0.f,0.f,0.f}};
    const size_t xb = (size_t)bb * Cin * PPAD;
    for (int kk = 0; kk < 9; ++kk) {
        int kh = kk / 3, kw = kk - (kk / 3) * 3;
        for (int k0 = 0; k0 < Cin; k0 += 32) {
            #pragma unroll
            for (int i = 0; i < 4; ++i) {
                int e = tid + 256 * i;
                int ci = e >> 5, p = e & 31;
                int pos = pos0 + p;
                float v = 0.f;
                if (pos < NPOS) {
                    int h = pos / NW, w = pos - (pos / NW) * NW;
                    v = xpad[xb + ((size_t)(k0 + ci) * PADW + h + kh) * PADW + w + kw];
                }
                As[ci][p] = v;
            }
            const float* wsrc = wt + ((size_t)kk * Cin + k0) * Cout + co0;
            #pragma unroll
            for (int i = 0; i < 8; ++i) {
                int e = tid + 256 * i;
                int ci = e >> 6, co = e & 63;
                Ws[ci][co] = wsrc[(size_t)ci * Cout + co];
            }
            __syncthreads();
            #pragma unroll
            for (int kc = 0; kc < 32; ++kc) {
                float4 a = *reinterpret_cast<const float4*>(&As[kc][tx * 4]);
                float b0 = Ws[kc][ty * 2], b1 = Ws[kc][ty * 2 + 1];
                acc[0][0] += b0 * a.x; acc[0][1] += b0 * a.y;
                acc[0][2] += b0 * a.z; acc[0][3] += b0 * a.w;
                acc[1][0] += b1 * a.x; acc[1][1] += b1 * a.y;
                acc[1][2] += b1 * a.z; acc[1][3] += b1 * a.w;
            }
            __syncthreads();
        }
    }
    #pragma unroll
    for (int j = 0; j < 2; ++j) {
        int co = co0 + ty * 2 + j;
        float bz = bias[co];
        #pragma unroll
        for (int i = 0; i < 4; ++i) {
            int pos = pos0 + tx * 4 + i;
            if (pos < NPOS) {
                int h = pos / NW, w = pos - (pos / NW) * NW;
                float v = acc[j][i] + bz;
                if (RELU) v = fmaxf(v, 0.f);
                ypad[(((size_t)bb * Cout + co) * PADW + h + 1) * PADW + w + 1] = v;
            }
        }
    }
}

// 3x3 conv 256->3, + bias, scaled by P, into padded fpad[b][3][39][39]
__global__ void conv3x3_small(const float* __restrict__ h1f, const float* __restrict__ w2,
                              const float* __restrict__ b2, float* __restrict__ fpad) {
    int idx = blockIdx.x * 256 + threadIdx.x;
    if (idx >= BB * NPOS) return;
    int bb = idx / NPOS, pos = idx - (idx / NPOS) * NPOS;
    int h = pos / NW, w = pos - (pos / NW) * NW;
    float a0 = b2[0], a1 = b2[1], a2 = b2[2];
    const float* xb = h1f + (size_t)bb * HID * PPAD;
    for (int ci = 0; ci < HID; ++ci) {
        const float* xr = xb + (size_t)ci * PPAD + h * PADW + w;
        #pragma unroll
        for (int kh = 0; kh < 3; ++kh) {
            #pragma unroll
            for (int kw = 0; kw < 3; ++kw) {
                float x = xr[kh * PADW + kw];
                int kidx = (ci * 3 + kh) * 3 + kw;
                a0 += x * w2[0 * HID * 9 + kidx];
                a1 += x * w2[1 * HID * 9 + kidx];
                a2 += x * w2[2 * HID * 9 + kidx];
            }
        }
    }
    size_t base = ((size_t)bb * 3) * PPAD;
    fpad[(base + 0 * PPAD) + (size_t)(h + 1) * PADW + w + 1] = 14.f * a0;
    fpad[(base + 1 * PPAD) + (size_t)(h + 1) * PADW + w + 1] = 14.f * a1;
    fpad[(base + 2 * PPAD) + (size_t)(h + 1) * PADW + w + 1] = 14.f * a2;
}

// Fused: 1x1 conv (256->1764) + softmax over 9 + neighbor einsum + pixel shuffle + sigmoid.
// 8 positions per block; wraw tile lives in LDS only.
#define POS_T 8
__global__ void wp2_fused(const float* __restrict__ h1w, const float* __restrict__ wt2,
                          const float* __restrict__ b2, const float* __restrict__ fpad,
                          float* __restrict__ out) {
    extern __shared__ float smem[];
    float* wr  = smem;                  // [8][1764]
    float* h1t = wr + POS_T * KOUT;     // [256][8]
    float* nbr = h1t + HID * POS_T;     // [8][3][9]
    int bb   = blockIdx.y;
    int pos0 = blockIdx.x * POS_T;
    int tid  = threadIdx.x;
    #pragma unroll
    for (int i = 0; i < 8; ++i) {
        int e = tid + 256 * i;
        int ci = e >> 3, p = e & 7;
        int pos = pos0 + p;
        float v = 0.f;
        if (pos < NPOS) {
            int h = pos / NW, w = pos - (pos / NW) * NW;
            v = h1w[(((size_t)bb * HID + ci) * PADW + h + 1) * PADW + w + 1];
        }
        h1t[ci * POS_T + p] = v;
    }
    if (tid < POS_T * 27) {
        int p = tid / 27, r = tid - (tid / 27) * 27;
        int c = r / 9, k = r - (r / 9) * 9;
        int i = k / 3, j = k - (k / 3) * 3;
        int pos = pos0 + p;
        float v = 0.f;
        if (pos < NPOS) {
            int h = pos / NW, w = pos - (pos / NW) * NW;
            v = fpad[(((size_t)bb * 3 + c) * PADW + h + i) * PADW + w + j];
        }
        nbr[(p * 3 + c) * 9 + k] = v;
    }
    __syncthreads();
    // GEMM phase: wraw[p][co] for co = tid + 256*it
    for (int it = 0; it < 7; ++it) {
        int co = tid + it * 256;
        if (co < KOUT) {
            float acc[POS_T];
            float bz = b2[co];
            #pragma unroll
            for (int p = 0; p < POS_T; ++p) acc[p] = bz;
            for (int ci = 0; ci < HID; ++ci) {
                float wv = wt2[(size_t)ci * KOUT + co];
                const float* hr = &h1t[ci * POS_T];
                #pragma unroll
                for (int p = 0; p < POS_T; ++p) acc[p] += wv * hr[p];
            }
            #pragma unroll
            for (int p = 0; p < POS_T; ++p) wr[p * KOUT + co] = acc[p];
        }
    }
    __syncthreads();
    // softmax over k (9) per (pos,pq) + combine neighbors + write
    for (int t = tid; t < POS_T * 196; t += 256) {
        int p = t / 196, pq = t - (t / 196) * 196;
        int pos = pos0 + p;
        if (pos >= NPOS) continue;
        float v[9];
        float m = -1e30f;
        #pragma unroll
        for (int k = 0; k < 9; ++k) { v[k] = wr[p * KOUT + k * 196 + pq]; m = fmaxf(m, v[k]); }
        float s = 0.f;
        #pragma unroll
        for (int k = 0; k < 9; ++k) { v[k] = __expf(v[k] - m); s += v[k]; }
        float inv = 1.f / s;
        int h = pos / NW, w = pos - (pos / NW) * NW;
        int pp = pq / PP, qq = pq - (pq / PP) * PP;
        int Y = h * PP + pp, X = w * PP + qq;
        float up[3];
        #pragma unroll
        for (int c = 0; c < 3; ++c) {
            const float* nb = &nbr[(p * 3 + c) * 9];
            float a = 0.f;
            #pragma unroll
            for (int k = 0; k < 9; ++k) a += v[k] * nb[k];
            up[c] = a * inv;
        }
        out[(((size_t)bb * 2 + 0) * HOUT + Y) * HOUT + X] = up[0];
        out[(((size_t)bb * 2 + 1) * HOUT + Y) * HOUT + X] = up[1];
        out[CONF_OFF + ((size_t)bb * HOUT + Y) * HOUT + X] = 1.f / (1.f + __expf(-up[2]));
    }
}

extern "C" void kernel_launch(void* const* d_in, const int* in_sizes, int n_in,
                              void* d_out, int out_size, void* d_ws, size_t ws_size,
                              hipStream_t stream) {
    const float* tokens = (const float*)d_in[0];
    const float* fh_w1  = (const float*)d_in[1];
    const float* fh_b1  = (const float*)d_in[2];
    const float* fh_w2  = (const float*)d_in[3];
    const float* fh_b2  = (const float*)d_in[4];
    const float* wp_w1  = (const float*)d_in[5];
    const float* wp_b1  = (const float*)d_in[6];
    const float* wp_w2  = (const float*)d_in[7];
    const float* wp_b2  = (const float*)d_in[8];
    float* out = (float*)d_out;

    float* ws   = (float*)d_ws;
    float* xpad = ws + OFF_XPAD;
    float* h1f  = ws + OFF_H1F;
    float* h1w  = ws + OFF_H1W;
    float* fpad = ws + OFF_FPAD;
    float* wt1f = ws + OFF_WT1F;
    float* wt1w = ws + OFF_WT1W;
    float* wt2  = ws + OFF_WT2;

    // zero padded activation buffers (borders must be 0)
    hipMemsetAsync(d_ws, 0, ACT_BYTES, stream);

    // weight transposes -> [kk][ci][co]
    {
        int total = 256 * 768 * 9;
        transpose_w<<<(total + 255) / 256, 256, 0, stream>>>(fh_w1, wt1f, 256, 768, 9);
        transpose_w<<<(total + 255) / 256, 256, 0, stream>>>(wp_w1, wt1w, 256, 768, 9);
        int t2 = KOUT * 256;
        transpose_w<<<(t2 + 255) / 256, 256, 0, stream>>>(wp_w2, wt2, KOUT, 256, 1);
    }

    // tokens -> xpad
    pack_tokens<<<dim3(22, 24, BB), 256, 0, stream>>>(tokens, xpad);

    // big convs
    dim3 g1((NPOS + 31) / 32, HID / 64, BB);
    conv3x3_fused<true><<<g1, 256, 0, stream>>>(xpad, wt1f, fh_b1, h1f, CIN, HID);
    conv3x3_fused<true><<<g1, 256, 0, stream>>>(xpad, wt1w, wp_b1, h1w, CIN, HID);

    // flow conv (256->3), scaled by P, into padded fpad
    conv3x3_small<<<(BB * NPOS + 255) / 256, 256, 0, stream>>>(h1f, fh_w2, fh_b2, fpad);

    // fused tail
    size_t smem = (size_t)(POS_T * KOUT + HID * POS_T + POS_T * 27) * sizeof(float);
    wp2_fused<<<dim3((NPOS + POS_T - 1) / POS_T, BB), 256, smem, stream>>>(h1w, wt2, wp_b2, fpad, out);
}

// Round 2
// 1325.327 us; speedup vs baseline: 3.2138x; 3.2138x over previous
//
#include <hip/hip_runtime.h>
#include <hip/hip_bf16.h>

// Problem constants
#define BB      16
#define CIN     768
#define HID     256
#define NCO     512       // both heads' conv1 outputs concatenated
#define NWI     37
#define NPOS    1369      // 37*37
#define PADW    39
#define PPAD    1521      // 39*39
#define PP      14
#define KOUT    1764      // 9*14*14
#define HOUT    518
#define CONF_OFF ((size_t)BB*2*HOUT*HOUT)

// Workspace layout (byte offsets)
//  h1f  : BB*HID*PPAD fp32 (padded, borders must be 0 — halo-read by conv3x3_small)
//  fpad : BB*3*PPAD  fp32 (padded, borders must be 0)
//  h1w  : BB*HID*PPAD fp32 (interior-only reads — no zeroing needed)
//  tokb : BB*NPOS*CIN bf16
//  wtb  : 9*NCO*CIN  bf16  ([kk][co][ci], ci contiguous)
//  wt2  : HID*KOUT   fp32  ([ci][co])
//  zero : 2 KiB zero page (redirect target for out-of-image conv taps)
static constexpr size_t B_H1F  = 0;
static constexpr size_t B_FPAD = B_H1F  + (size_t)BB*HID*PPAD*4;
static constexpr size_t B_H1W  = B_FPAD + (size_t)BB*3*PPAD*4;
static constexpr size_t B_TOK  = B_H1W  + (size_t)BB*HID*PPAD*4;
static constexpr size_t B_WTB  = B_TOK  + (size_t)BB*NPOS*CIN*2;
static constexpr size_t B_WT2  = B_WTB  + (size_t)9*NCO*CIN*2;
static constexpr size_t B_ZERO = B_WT2  + (size_t)HID*KOUT*4;
// total ~92.7 MiB + 2 KiB

typedef __attribute__((ext_vector_type(8))) __bf16 bf16x8;
typedef __attribute__((ext_vector_type(4))) float  f32x4;

__device__ __forceinline__ void gl_lds16(const void* g, void* l) {
    __builtin_amdgcn_global_load_lds(
        (const __attribute__((address_space(1))) unsigned int*)g,
        (__attribute__((address_space(3))) unsigned int*)l, 16, 0, 0);
}

// tokens fp32 -> bf16 (same [b][pos][ci] layout)
__global__ void cast_tok(const float* __restrict__ t, __hip_bfloat16* __restrict__ o, int n4) {
    for (int i = blockIdx.x * 256 + threadIdx.x; i < n4; i += gridDim.x * 256) {
        float4 v = reinterpret_cast<const float4*>(t)[i];
        union { __hip_bfloat16 h[4]; short4 s; } u;
        u.h[0] = __float2bfloat16(v.x); u.h[1] = __float2bfloat16(v.y);
        u.h[2] = __float2bfloat16(v.z); u.h[3] = __float2bfloat16(v.w);
        reinterpret_cast<short4*>(o)[i] = u.s;
    }
}

// fh_w1/wp_w1 [co][ci][3][3] -> wtb[kk][co(512)][ci] bf16
__global__ void build_wtb(const float* __restrict__ fh, const float* __restrict__ wp,
                          __hip_bfloat16* __restrict__ wtb) {
    int idx = blockIdx.x * 256 + threadIdx.x;
    if (idx >= 9 * NCO * CIN) return;
    int ci = idx % CIN;
    int r  = idx / CIN;
    int co = r % NCO;
    int kk = r / NCO;
    float v = (co < HID) ? fh[((size_t)co * CIN + ci) * 9 + kk]
                         : wp[((size_t)(co - HID) * CIN + ci) * 9 + kk];
    wtb[idx] = __float2bfloat16(v);
}

// w[co][ci] -> wt[ci][co]   (for the 1x1 wp2 conv, fp32)
__global__ void transpose_w(const float* __restrict__ w, float* __restrict__ wt,
                            int Cout, int Cin, int KK) {
    int idx = blockIdx.x * 256 + threadIdx.x;
    int total = Cout * Cin * KK;
    if (idx >= total) return;
    int co = idx % Cout;
    int r  = idx / Cout;
    int ci = r % Cin;
    wt[idx] = w[((size_t)co * Cin + ci) * KK];
}

// Implicit-GEMM 3x3 conv via MFMA: M=positions(128/block), N=co(128/block), K=9*768.
// A = shifted token rows (per-lane global addr; invalid taps -> zero page).
// B = wtb[kk][co][ci]. Epilogue: bias + ReLU -> padded fp32 h1f / h1w.
__global__ void conv1_mfma(const __hip_bfloat16* __restrict__ tok,
                           const __hip_bfloat16* __restrict__ wtb,
                           const float* __restrict__ fh_b1, const float* __restrict__ wp_b1,
                           const char* __restrict__ zpage,
                           float* __restrict__ h1f, float* __restrict__ h1w) {
    __shared__ __align__(16) __hip_bfloat16 As[128 * 64];   // [pos][k]  (row = 128B)
    __shared__ __align__(16) __hip_bfloat16 Bs[128 * 64];   // [co][k]
    const int bb   = blockIdx.z;
    const int pos0 = blockIdx.x * 128;
    const int co0  = blockIdx.y * 128;
    const int tid  = threadIdx.x;
    const int wv   = tid >> 6, lane = tid & 63;
    const int wr   = wv >> 1,  wc   = wv & 1;

    // --- staging geometry: issue i stages 1KB chunk c=wv*4+i; lane covers
    //     row = c*8 + lane/8, 8 bf16 at k-offset (lane%8)*8 ---
    const int cig = (lane & 7) * 8;           // k offset within BK=64 (elements)
    int h_i[4], w_i[4]; bool inb[4];
    const char* bsrcb[4];
    char *alds[4], *blds[4];
    #pragma unroll
    for (int i = 0; i < 4; ++i) {
        int c   = wv * 4 + i;
        int row = c * 8 + (lane >> 3);
        int pos = pos0 + row;
        inb[i] = pos < NPOS;
        h_i[i] = pos / NWI;
        w_i[i] = pos % NWI;
        bsrcb[i] = (const char*)wtb + (((size_t)(co0 + row)) * CIN + cig) * 2;
        alds[i]  = (char*)As + c * 1024;
        blds[i]  = (char*)Bs + c * 1024;
    }

    f32x4 acc[4][4] = {};

    const char* apx = (const char*)As + ((wr * 64 + (lane & 15)) * 64) * 2 + (lane >> 4) * 16;
    const char* bpx = (const char*)Bs + ((wc * 64 + (lane & 15)) * 64) * 2 + (lane >> 4) * 16;

    for (int kk = 0; kk < 9; ++kk) {
        const int dh = kk / 3 - 1, dw = kk % 3 - 1;
        const size_t kkoff = (size_t)kk * NCO * CIN * 2;
        const char* asrc[4];
        #pragma unroll
        for (int i = 0; i < 4; ++i) {
            int hh = h_i[i] + dh, ww = w_i[i] + dw;
            bool v = inb[i] && (unsigned)hh < NWI && (unsigned)ww < NWI;
            asrc[i] = v ? (const char*)tok + (((size_t)bb * NPOS + hh * NWI + ww) * CIN + cig) * 2
                        : zpage;
        }
        for (int k0 = 0; k0 < CIN; k0 += 64) {
            const int kb = k0 * 2;
            #pragma unroll
            for (int i = 0; i < 4; ++i) gl_lds16(asrc[i] + kb, alds[i]);
            #pragma unroll
            for (int i = 0; i < 4; ++i) gl_lds16(bsrcb[i] + kkoff + kb, blds[i]);
            __syncthreads();
            #pragma unroll
            for (int s = 0; s < 2; ++s) {
                bf16x8 af[4], bf[4];
                #pragma unroll
                for (int mf = 0; mf < 4; ++mf)
                    af[mf] = *reinterpret_cast<const bf16x8*>(apx + mf * 16 * 128 + s * 64);
                #pragma unroll
                for (int nf = 0; nf < 4; ++nf)
                    bf[nf] = *reinterpret_cast<const bf16x8*>(bpx + nf * 16 * 128 + s * 64);
                #pragma unroll
                for (int mf = 0; mf < 4; ++mf)
                    #pragma unroll
                    for (int nf = 0; nf < 4; ++nf)
                        acc[mf][nf] = __builtin_amdgcn_mfma_f32_16x16x32_bf16(
                            af[mf], bf[nf], acc[mf][nf], 0, 0, 0);
            }
            __syncthreads();
        }
    }

    // epilogue: C/D mapping (m89): n = lane&15, m = (lane>>4)*4 + r
    const bool  isF   = (co0 < HID);         // uniform per block (co tile 128)
    const float* bias = isF ? fh_b1 : wp_b1;
    float* dst        = isF ? h1f : h1w;
    const int cobase  = isF ? co0 : co0 - HID;
    const int nl = lane & 15, mh = (lane >> 4) * 4;
    #pragma unroll
    for (int mf = 0; mf < 4; ++mf) {
        #pragma unroll
        for (int r = 0; r < 4; ++r) {
            int pos = pos0 + wr * 64 + mf * 16 + mh + r;
            if (pos >= NPOS) continue;
            int h = pos / NWI, w = pos % NWI;
            #pragma unroll
            for (int nf = 0; nf < 4; ++nf) {
                int c = cobase + wc * 64 + nf * 16 + nl;
                float v = fmaxf(acc[mf][nf][r] + bias[c], 0.f);
                dst[(((size_t)bb * HID + c) * PADW + h + 1) * PADW + w + 1] = v;
            }
        }
    }
}

// 3x3 conv 256->3, + bias, scaled by P, into padded fpad[b][3][39][39]
__global__ void conv3x3_small(const float* __restrict__ h1f, const float* __restrict__ w2,
                              const float* __restrict__ b2, float* __restrict__ fpad) {
    int idx = blockIdx.x * 256 + threadIdx.x;
    if (idx >= BB * NPOS) return;
    int bb = idx / NPOS, pos = idx - (idx / NPOS) * NPOS;
    int h = pos / NWI, w = pos - (pos / NWI) * NWI;
    float a0 = b2[0], a1 = b2[1], a2 = b2[2];
    const float* xb = h1f + (size_t)bb * HID * PPAD;
    for (int ci = 0; ci < HID; ++ci) {
        const float* xr = xb + (size_t)ci * PPAD + h * PADW + w;
        #pragma unroll
        for (int kh = 0; kh < 3; ++kh) {
            #pragma unroll
            for (int kw = 0; kw < 3; ++kw) {
                float x = xr[kh * PADW + kw];
                int kidx = (ci * 3 + kh) * 3 + kw;
                a0 += x * w2[0 * HID * 9 + kidx];
                a1 += x * w2[1 * HID * 9 + kidx];
                a2 += x * w2[2 * HID * 9 + kidx];
            }
        }
    }
    size_t base = ((size_t)bb * 3) * PPAD;
    fpad[(base + 0 * PPAD) + (size_t)(h + 1) * PADW + w + 1] = 14.f * a0;
    fpad[(base + 1 * PPAD) + (size_t)(h + 1) * PADW + w + 1] = 14.f * a1;
    fpad[(base + 2 * PPAD) + (size_t)(h + 1) * PADW + w + 1] = 14.f * a2;
}

// Fused: 1x1 conv (256->1764) + softmax over 9 + neighbor einsum + pixel shuffle + sigmoid.
#define POS_T 8
__global__ void wp2_fused(const float* __restrict__ h1w, const float* __restrict__ wt2,
                          const float* __restrict__ b2, const float* __restrict__ fpad,
                          float* __restrict__ out) {
    extern __shared__ float smem[];
    float* wr  = smem;                  // [8][1764]
    float* h1t = wr + POS_T * KOUT;     // [256][8]
    float* nbr = h1t + HID * POS_T;     // [8][3][9]
    int bb   = blockIdx.y;
    int pos0 = blockIdx.x * POS_T;
    int tid  = threadIdx.x;
    #pragma unroll
    for (int i = 0; i < 8; ++i) {
        int e = tid + 256 * i;
        int ci = e >> 3, p = e & 7;
        int pos = pos0 + p;
        float v = 0.f;
        if (pos < NPOS) {
            int h = pos / NWI, w = pos - (pos / NWI) * NWI;
            v = h1w[(((size_t)bb * HID + ci) * PADW + h + 1) * PADW + w + 1];
        }
        h1t[ci * POS_T + p] = v;
    }
    if (tid < POS_T * 27) {
        int p = tid / 27, r = tid - (tid / 27) * 27;
        int c = r / 9, k = r - (r / 9) * 9;
        int i = k / 3, j = k - (k / 3) * 3;
        int pos = pos0 + p;
        float v = 0.f;
        if (pos < NPOS) {
            int h = pos / NWI, w = pos - (pos / NWI) * NWI;
            v = fpad[(((size_t)bb * 3 + c) * PADW + h + i) * PADW + w + j];
        }
        nbr[(p * 3 + c) * 9 + k] = v;
    }
    __syncthreads();
    for (int it = 0; it < 7; ++it) {
        int co = tid + it * 256;
        if (co < KOUT) {
            float acc[POS_T];
            float bz = b2[co];
            #pragma unroll
            for (int p = 0; p < POS_T; ++p) acc[p] = bz;
            for (int ci = 0; ci < HID; ++ci) {
                float wv = wt2[(size_t)ci * KOUT + co];
                const float* hr = &h1t[ci * POS_T];
                #pragma unroll
                for (int p = 0; p < POS_T; ++p) acc[p] += wv * hr[p];
            }
            #pragma unroll
            for (int p = 0; p < POS_T; ++p) wr[p * KOUT + co] = acc[p];
        }
    }
    __syncthreads();
    for (int t = tid; t < POS_T * 196; t += 256) {
        int p = t / 196, pq = t - (t / 196) * 196;
        int pos = pos0 + p;
        if (pos >= NPOS) continue;
        float v[9];
        float m = -1e30f;
        #pragma unroll
        for (int k = 0; k < 9; ++k) { v[k] = wr[p * KOUT + k * 196 + pq]; m = fmaxf(m, v[k]); }
        float s = 0.f;
        #pragma unroll
        for (int k = 0; k < 9; ++k) { v[k] = __expf(v[k] - m); s += v[k]; }
        float inv = 1.f / s;
        int h = pos / NWI, w = pos - (pos / NWI) * NWI;
        int pp = pq / PP, qq = pq - (pq / PP) * PP;
        int Y = h * PP + pp, X = w * PP + qq;
        float up[3];
        #pragma unroll
        for (int c = 0; c < 3; ++c) {
            const float* nb = &nbr[(p * 3 + c) * 9];
            float a = 0.f;
            #pragma unroll
            for (int k = 0; k < 9; ++k) a += v[k] * nb[k];
            up[c] = a * inv;
        }
        out[(((size_t)bb * 2 + 0) * HOUT + Y) * HOUT + X] = up[0];
        out[(((size_t)bb * 2 + 1) * HOUT + Y) * HOUT + X] = up[1];
        out[CONF_OFF + ((size_t)bb * HOUT + Y) * HOUT + X] = 1.f / (1.f + __expf(-up[2]));
    }
}

extern "C" void kernel_launch(void* const* d_in, const int* in_sizes, int n_in,
                              void* d_out, int out_size, void* d_ws, size_t ws_size,
                              hipStream_t stream) {
    const float* tokens = (const float*)d_in[0];
    const float* fh_w1  = (const float*)d_in[1];
    const float* fh_b1  = (const float*)d_in[2];
    const float* fh_w2  = (const float*)d_in[3];
    const float* fh_b2  = (const float*)d_in[4];
    const float* wp_w1  = (const float*)d_in[5];
    const float* wp_b1  = (const float*)d_in[6];
    const float* wp_w2  = (const float*)d_in[7];
    const float* wp_b2  = (const float*)d_in[8];
    float* out = (float*)d_out;

    char* ws = (char*)d_ws;
    float*           h1f  = (float*)(ws + B_H1F);
    float*           fpad = (float*)(ws + B_FPAD);
    float*           h1w  = (float*)(ws + B_H1W);
    __hip_bfloat16*  tokb = (__hip_bfloat16*)(ws + B_TOK);
    __hip_bfloat16*  wtb  = (__hip_bfloat16*)(ws + B_WTB);
    float*           wt2  = (float*)(ws + B_WT2);
    const char*      zp   = (const char*)(ws + B_ZERO);

    // zero: h1f + fpad (padded borders), zero page (ws is re-poisoned each launch)
    hipMemsetAsync(ws + B_H1F, 0, B_H1W - B_H1F, stream);
    hipMemsetAsync(ws + B_ZERO, 0, 2048, stream);

    // packing
    cast_tok<<<2048, 256, 0, stream>>>(tokens, tokb, BB * NPOS * CIN / 4);
    build_wtb<<<(9 * NCO * CIN + 255) / 256, 256, 0, stream>>>(fh_w1, wp_w1, wtb);
    transpose_w<<<(KOUT * HID + 255) / 256, 256, 0, stream>>>(wp_w2, wt2, KOUT, HID, 1);

    // big conv pair as one MFMA implicit GEMM
    conv1_mfma<<<dim3(11, 4, BB), 256, 0, stream>>>(tokb, wtb, fh_b1, wp_b1, zp, h1f, h1w);

    // flow conv (256->3), scaled by P, into padded fpad
    conv3x3_small<<<(BB * NPOS + 255) / 256, 256, 0, stream>>>(h1f, fh_w2, fh_b2, fpad);

    // fused tail
    size_t smem = (size_t)(POS_T * KOUT + HID * POS_T + POS_T * 27) * sizeof(float);
    wp2_fused<<<dim3((NPOS + POS_T - 1) / POS_T, BB), 256, smem, stream>>>(h1w, wt2, wp_b2, fpad, out);
}

// Round 5
// 682.374 us; speedup vs baseline: 6.2419x; 1.9422x over previous
//
#include <hip/hip_runtime.h>
#include <hip/hip_bf16.h>

// Problem constants
#define BB      16
#define CIN     768
#define HID     256
#define NCO     512       // both heads' conv1 outputs concatenated
#define NWI     37
#define NPOS    1369      // 37*37
#define PADW    39
#define PPAD    1521      // 39*39
#define PP      14
#define KOUT    1764      // 9*14*14
#define KOUTP   1792      // padded to 7*256
#define HOUT    518
#define CONF_OFF ((size_t)BB*2*HOUT*HOUT)
#define WSTR    1802      // wraw LDS row stride (bf16), padded: bank-spread

// Workspace layout (byte offsets)
//  h1f  : BB*HID*PPAD fp32 (padded; borders must be 0 — halo-read by conv3_small)
//  fpad : BB*3*PPAD  fp32 (padded; borders must be 0)
//  h1wb : BB*NPOS*HID bf16  ([b][pos][ci] — GEMM-friendly, 1x1 conv needs no halo)
//  tokb : BB*NPOS*CIN bf16
//  wtb  : 9*NCO*CIN  bf16  ([kk][co][ci])
//  wt2b : KOUTP*HID  bf16  ([co][ci], rows >=KOUT zero)
//  zero : 2 KiB zero page (redirect target for out-of-image conv taps)
static constexpr size_t B_H1F  = 0;
static constexpr size_t B_FPAD = B_H1F  + (size_t)BB*HID*PPAD*4;
static constexpr size_t B_H1WB = B_FPAD + (size_t)BB*3*PPAD*4;
static constexpr size_t B_TOK  = B_H1WB + (size_t)BB*NPOS*HID*2;
static constexpr size_t B_WTB  = B_TOK  + (size_t)BB*NPOS*CIN*2;
static constexpr size_t B_WT2B = B_WTB  + (size_t)9*NCO*CIN*2;
static constexpr size_t B_ZERO = B_WT2B + (size_t)KOUTP*HID*2;
// total ~74.5 MiB + 2 KiB

typedef __attribute__((ext_vector_type(8))) __bf16 bf16x8;
typedef __attribute__((ext_vector_type(4))) float  f32x4;

__device__ __forceinline__ void gl_lds16(const void* g, void* l) {
    __builtin_amdgcn_global_load_lds(
        (const __attribute__((address_space(1))) unsigned int*)g,
        (__attribute__((address_space(3))) unsigned int*)l, 16, 0, 0);
}

// tokens fp32 -> bf16 (same [b][pos][ci] layout)
__global__ void cast_tok(const float* __restrict__ t, __hip_bfloat16* __restrict__ o, int n4) {
    for (int i = blockIdx.x * 256 + threadIdx.x; i < n4; i += gridDim.x * 256) {
        float4 v = reinterpret_cast<const float4*>(t)[i];
        union { __hip_bfloat16 h[4]; short4 s; } u;
        u.h[0] = __float2bfloat16(v.x); u.h[1] = __float2bfloat16(v.y);
        u.h[2] = __float2bfloat16(v.z); u.h[3] = __float2bfloat16(v.w);
        reinterpret_cast<short4*>(o)[i] = u.s;
    }
}

// fh_w1/wp_w1 [co][ci][3][3] -> wtb[kk][co(512)][ci] bf16
__global__ void build_wtb(const float* __restrict__ fh, const float* __restrict__ wp,
                          __hip_bfloat16* __restrict__ wtb) {
    int idx = blockIdx.x * 256 + threadIdx.x;
    if (idx >= 9 * NCO * CIN) return;
    int ci = idx % CIN;
    int r  = idx / CIN;
    int co = r % NCO;
    int kk = r / NCO;
    float v = (co < HID) ? fh[((size_t)co * CIN + ci) * 9 + kk]
                         : wp[((size_t)(co - HID) * CIN + ci) * 9 + kk];
    wtb[idx] = __float2bfloat16(v);
}

// wp_w2 [KOUT][HID][1][1] -> wt2b [KOUTP][HID] bf16 (pad rows zero)
__global__ void cast_wt2b(const float* __restrict__ w, __hip_bfloat16* __restrict__ o) {
    int idx = blockIdx.x * 256 + threadIdx.x;
    if (idx >= KOUTP * HID) return;
    int co = idx / HID;
    o[idx] = (co < KOUT) ? __float2bfloat16(w[idx]) : __hip_bfloat16(0.f);
}

// Implicit-GEMM 3x3 conv via MFMA: M=positions(128/block), N=co(128/block), K=9*768.
__global__ void conv1_mfma(const __hip_bfloat16* __restrict__ tok,
                           const __hip_bfloat16* __restrict__ wtb,
                           const float* __restrict__ fh_b1, const float* __restrict__ wp_b1,
                           const char* __restrict__ zpage,
                           float* __restrict__ h1f, __hip_bfloat16* __restrict__ h1wb) {
    __shared__ __align__(16) __hip_bfloat16 As[128 * 64];   // [pos][k]
    __shared__ __align__(16) __hip_bfloat16 Bs[128 * 64];   // [co][k]
    const int bb   = blockIdx.z;
    const int pos0 = blockIdx.x * 128;
    const int co0  = blockIdx.y * 128;
    const int tid  = threadIdx.x;
    const int wv   = tid >> 6, lane = tid & 63;
    const int wr   = wv >> 1,  wc   = wv & 1;

    const int cig = (lane & 7) * 8;           // k offset within BK=64 (elements)
    int h_i[4], w_i[4]; bool inb[4];
    const char* bsrcb[4];
    char *alds[4], *blds[4];
    #pragma unroll
    for (int i = 0; i < 4; ++i) {
        int c   = wv * 4 + i;
        int row = c * 8 + (lane >> 3);
        int pos = pos0 + row;
        inb[i] = pos < NPOS;
        h_i[i] = pos / NWI;
        w_i[i] = pos % NWI;
        bsrcb[i] = (const char*)wtb + (((size_t)(co0 + row)) * CIN + cig) * 2;
        alds[i]  = (char*)As + c * 1024;
        blds[i]  = (char*)Bs + c * 1024;
    }

    f32x4 acc[4][4] = {};

    const char* apx = (const char*)As + ((wr * 64 + (lane & 15)) * 64) * 2 + (lane >> 4) * 16;
    const char* bpx = (const char*)Bs + ((wc * 64 + (lane & 15)) * 64) * 2 + (lane >> 4) * 16;

    for (int kk = 0; kk < 9; ++kk) {
        const int dh = kk / 3 - 1, dw = kk % 3 - 1;
        const size_t kkoff = (size_t)kk * NCO * CIN * 2;
        const char* asrc[4];
        #pragma unroll
        for (int i = 0; i < 4; ++i) {
            int hh = h_i[i] + dh, ww = w_i[i] + dw;
            bool v = inb[i] && (unsigned)hh < NWI && (unsigned)ww < NWI;
            asrc[i] = v ? (const char*)tok + (((size_t)bb * NPOS + hh * NWI + ww) * CIN + cig) * 2
                        : zpage;
        }
        for (int k0 = 0; k0 < CIN; k0 += 64) {
            const int kb = k0 * 2;
            #pragma unroll
            for (int i = 0; i < 4; ++i) gl_lds16(asrc[i] + kb, alds[i]);
            #pragma unroll
            for (int i = 0; i < 4; ++i) gl_lds16(bsrcb[i] + kkoff + kb, blds[i]);
            __syncthreads();
            #pragma unroll
            for (int s = 0; s < 2; ++s) {
                bf16x8 af[4], bf[4];
                #pragma unroll
                for (int mf = 0; mf < 4; ++mf)
                    af[mf] = *reinterpret_cast<const bf16x8*>(apx + mf * 16 * 128 + s * 64);
                #pragma unroll
                for (int nf = 0; nf < 4; ++nf)
                    bf[nf] = *reinterpret_cast<const bf16x8*>(bpx + nf * 16 * 128 + s * 64);
                #pragma unroll
                for (int mf = 0; mf < 4; ++mf)
                    #pragma unroll
                    for (int nf = 0; nf < 4; ++nf)
                        acc[mf][nf] = __builtin_amdgcn_mfma_f32_16x16x32_bf16(
                            af[mf], bf[nf], acc[mf][nf], 0, 0, 0);
            }
            __syncthreads();
        }
    }

    // epilogue: C/D mapping (m89): n = lane&15, m = (lane>>4)*4 + r
    const bool  isF   = (co0 < HID);
    const float* bias = isF ? fh_b1 : wp_b1;
    const int cobase  = isF ? co0 : co0 - HID;
    const int nl = lane & 15, mh = (lane >> 4) * 4;
    #pragma unroll
    for (int mf = 0; mf < 4; ++mf) {
        #pragma unroll
        for (int r = 0; r < 4; ++r) {
            int pos = pos0 + wr * 64 + mf * 16 + mh + r;
            if (pos >= NPOS) continue;
            int h = pos / NWI, w = pos % NWI;
            #pragma unroll
            for (int nf = 0; nf < 4; ++nf) {
                int c = cobase + wc * 64 + nf * 16 + nl;
                float v = fmaxf(acc[mf][nf][r] + bias[c], 0.f);
                if (isF)
                    h1f[(((size_t)bb * HID + c) * PADW + h + 1) * PADW + w + 1] = v;
                else
                    h1wb[((size_t)bb * NPOS + pos) * HID + c] = __float2bfloat16(v);
            }
        }
    }
}

// 3x3 conv 256->3 (+bias, xP) -> padded fpad. 32 pos x 8 ci-groups per block.
__global__ __launch_bounds__(256) void conv3_small(const float* __restrict__ h1f,
                                                   const float* __restrict__ w2,
                                                   const float* __restrict__ b2,
                                                   float* __restrict__ fpad) {
    __shared__ float red[8][3][32];
    int tid = threadIdx.x;
    int pl = tid & 31, cg = tid >> 5;
    int idx = blockIdx.x * 32 + pl;
    int bb = 0, pos = 0;
    if (idx < BB * NPOS) { bb = idx / NPOS; pos = idx % NPOS; }
    int h = pos / NWI, w = pos % NWI;
    float a0 = 0.f, a1 = 0.f, a2 = 0.f;
    const float* xb = h1f + ((size_t)bb * HID + cg * 32) * PPAD;
    const float* wb = w2 + cg * 32 * 9;
    for (int cl = 0; cl < 32; ++cl) {
        const float* xr = xb + (size_t)cl * PPAD + h * PADW + w;
        #pragma unroll
        for (int kk = 0; kk < 9; ++kk) {
            float x = xr[(kk / 3) * PADW + (kk % 3)];
            a0 += x * wb[cl * 9 + kk];
            a1 += x * wb[2304 + cl * 9 + kk];
            a2 += x * wb[4608 + cl * 9 + kk];
        }
    }
    red[cg][0][pl] = a0; red[cg][1][pl] = a1; red[cg][2][pl] = a2;
    __syncthreads();
    if (tid < 96) {
        int c = tid >> 5, p2 = tid & 31;
        float s = 0.f;
        #pragma unroll
        for (int q = 0; q < 8; ++q) s += red[q][c][p2];
        int idx2 = blockIdx.x * 32 + p2;
        if (idx2 < BB * NPOS) {
            int b2i = idx2 / NPOS, ps = idx2 % NPOS;
            int hh = ps / NWI, ww = ps % NWI;
            fpad[(((size_t)b2i * 3 + c) * PADW + hh + 1) * PADW + ww + 1] = 14.f * (s + b2[c]);
        }
    }
}

// MFMA 1x1 conv (256->1792) + softmax(9) + neighbor einsum + pixel shuffle + sigmoid.
// M=16 positions/block; wraw tile bf16 in LDS; B streamed from L2.
__global__ __launch_bounds__(256) void wp2_mfma(const __hip_bfloat16* __restrict__ h1wb,
                                                const __hip_bfloat16* __restrict__ wt2b,
                                                const float* __restrict__ b2,
                                                const float* __restrict__ fpad,
                                                float* __restrict__ out) {
    extern __shared__ char smem[];
    __hip_bfloat16* wraw = (__hip_bfloat16*)smem;              // [16][WSTR]
    float* nbr = (float*)(smem + (size_t)16 * WSTR * 2);       // [16][27]
    const int bb = blockIdx.y, pos0 = blockIdx.x * 16;
    const int tid = threadIdx.x, wv = tid >> 6, lane = tid & 63;
    const int nl = lane & 15, g = lane >> 4;

    // neighbor staging (padded fpad: borders zero)
    for (int e = tid; e < 16 * 27; e += 256) {
        int p = e / 27, r = e % 27;
        int c = r / 9, k = r % 9;
        int i = k / 3, j = k % 3;
        int pos = pos0 + p; float v = 0.f;
        if (pos < NPOS) {
            int h = pos / NWI, w = pos % NWI;
            v = fpad[(((size_t)bb * 3 + c) * PADW + h + i) * PADW + w + j];
        }
        nbr[p * 27 + r] = v;
    }

    // A fragments: 16 pos x K=256, held in registers
    int posc = pos0 + nl; if (posc >= NPOS) posc = NPOS - 1;
    const __hip_bfloat16* arow = h1wb + ((size_t)bb * NPOS + posc) * HID + g * 8;
    bf16x8 af[8];
    #pragma unroll
    for (int s = 0; s < 8; ++s) af[s] = *reinterpret_cast<const bf16x8*>(arow + s * 32);

    // GEMM: 7 co-chunks of 256 (64 per wave)
    for (int it = 0; it < 7; ++it) {
        const int cob = it * 256 + wv * 64;
        #pragma unroll
        for (int nf = 0; nf < 4; ++nf) {
            const int co = cob + nf * 16 + nl;
            const __hip_bfloat16* brow = wt2b + (size_t)co * HID + g * 8;
            f32x4 a = {0.f, 0.f, 0.f, 0.f};
            #pragma unroll
            for (int s = 0; s < 8; ++s) {
                bf16x8 bf = *reinterpret_cast<const bf16x8*>(brow + s * 32);
                a = __builtin_amdgcn_mfma_f32_16x16x32_bf16(af[s], bf, a, 0, 0, 0);
            }
            float bz = (co < KOUT) ? b2[co] : 0.f;
            #pragma unroll
            for (int r = 0; r < 4; ++r)
                wraw[(g * 4 + r) * WSTR + co] = __float2bfloat16(a[r] + bz);
        }
    }
    __syncthreads();

    // softmax(9) + einsum + pixel shuffle + sigmoid
    for (int t = tid; t < 16 * 196; t += 256) {
        int p = t / 196, pq = t % 196;
        int pos = pos0 + p; if (pos >= NPOS) continue;
        float v[9]; float m = -1e30f;
        #pragma unroll
        for (int k = 0; k < 9; ++k) {
            v[k] = __bfloat162float(wraw[p * WSTR + k * 196 + pq]);
            m = fmaxf(m, v[k]);
        }
        float s = 0.f;
        #pragma unroll
        for (int k = 0; k < 9; ++k) { v[k] = __expf(v[k] - m); s += v[k]; }
        float inv = 1.f / s;
        int h = pos / NWI, w = pos % NWI;
        int pp = pq / PP, qq = pq % PP;
        int Y = h * PP + pp, X = w * PP + qq;
        const float* nb = &nbr[p * 27];
        float u0 = 0.f, u1 = 0.f, u2 = 0.f;
        #pragma unroll
        for (int k = 0; k < 9; ++k) {
            u0 += v[k] * nb[k]; u1 += v[k] * nb[9 + k]; u2 += v[k] * nb[18 + k];
        }
        out[(((size_t)bb * 2 + 0) * HOUT + Y) * HOUT + X] = u0 * inv;
        out[(((size_t)bb * 2 + 1) * HOUT + Y) * HOUT + X] = u1 * inv;
        out[CONF_OFF + ((size_t)bb * HOUT + Y) * HOUT + X] = 1.f / (1.f + __expf(-u2 * inv));
    }
}

extern "C" void kernel_launch(void* const* d_in, const int* in_sizes, int n_in,
                              void* d_out, int out_size, void* d_ws, size_t ws_size,
                              hipStream_t stream) {
    const float* tokens = (const float*)d_in[0];
    const float* fh_w1  = (const float*)d_in[1];
    const float* fh_b1  = (const float*)d_in[2];
    const float* fh_w2  = (const float*)d_in[3];
    const float* fh_b2  = (const float*)d_in[4];
    const float* wp_w1  = (const float*)d_in[5];
    const float* wp_b1  = (const float*)d_in[6];
    const float* wp_w2  = (const float*)d_in[7];
    const float* wp_b2  = (const float*)d_in[8];
    float* out = (float*)d_out;

    char* ws = (char*)d_ws;
    float*           h1f  = (float*)(ws + B_H1F);
    float*           fpad = (float*)(ws + B_FPAD);
    __hip_bfloat16*  h1wb = (__hip_bfloat16*)(ws + B_H1WB);
    __hip_bfloat16*  tokb = (__hip_bfloat16*)(ws + B_TOK);
    __hip_bfloat16*  wtb  = (__hip_bfloat16*)(ws + B_WTB);
    __hip_bfloat16*  wt2b = (__hip_bfloat16*)(ws + B_WT2B);
    const char*      zp   = (const char*)(ws + B_ZERO);

    // zero padded fp32 activation buffers (h1f+fpad) + zero page
    hipMemsetAsync(ws + B_H1F, 0, B_H1WB - B_H1F, stream);
    hipMemsetAsync(ws + B_ZERO, 0, 2048, stream);

    // packing
    cast_tok<<<2048, 256, 0, stream>>>(tokens, tokb, BB * NPOS * CIN / 4);
    build_wtb<<<(9 * NCO * CIN + 255) / 256, 256, 0, stream>>>(fh_w1, wp_w1, wtb);
    cast_wt2b<<<(KOUTP * HID + 255) / 256, 256, 0, stream>>>(wp_w2, wt2b);

    // big conv pair as one MFMA implicit GEMM
    conv1_mfma<<<dim3(11, 4, BB), 256, 0, stream>>>(tokb, wtb, fh_b1, wp_b1, zp, h1f, h1wb);

    // flow conv (256->3), scaled by P, into padded fpad
    conv3_small<<<(BB * NPOS + 31) / 32, 256, 0, stream>>>(h1f, fh_w2, fh_b2, fpad);

    // fused MFMA tail
    size_t smem = (size_t)16 * WSTR * 2 + (size_t)16 * 27 * 4;
    wp2_mfma<<<dim3((NPOS + 15) / 16, BB), 256, smem, stream>>>(h1wb, wt2b, wp_b2, fpad, out);
}

// Round 6
// 613.841 us; speedup vs baseline: 6.9388x; 1.1116x over previous
//
#include <hip/hip_runtime.h>
#include <hip/hip_bf16.h>

// Problem constants
#define BB      16
#define CIN     768
#define HID     256
#define NCO     512       // both heads' conv1 outputs concatenated
#define NWI     37
#define NPOS    1369      // 37*37
#define PADW    39
#define PPAD    1521      // 39*39
#define PP      14
#define KOUT    1764      // 9*14*14
#define KOUTP   1792      // padded to 7*256
#define HOUT    518
#define CONF_OFF ((size_t)BB*2*HOUT*HOUT)
#define WSTR    1802      // wraw LDS row stride (bf16), padded: bank-spread

// Workspace layout (byte offsets)
static constexpr size_t B_H1F  = 0;
static constexpr size_t B_FPAD = B_H1F  + (size_t)BB*HID*PPAD*4;
static constexpr size_t B_H1WB = B_FPAD + (size_t)BB*3*PPAD*4;
static constexpr size_t B_TOK  = B_H1WB + (size_t)BB*NPOS*HID*2;
static constexpr size_t B_WTB  = B_TOK  + (size_t)BB*NPOS*CIN*2;
static constexpr size_t B_WT2B = B_WTB  + (size_t)9*NCO*CIN*2;
static constexpr size_t B_ZERO = B_WT2B + (size_t)KOUTP*HID*2;
// total ~74.5 MiB + 2 KiB

typedef __attribute__((ext_vector_type(8))) __bf16 bf16x8;
typedef __attribute__((ext_vector_type(4))) float  f32x4;

__device__ __forceinline__ void gl_lds16(const void* g, void* l) {
    __builtin_amdgcn_global_load_lds(
        (const __attribute__((address_space(1))) unsigned int*)g,
        (__attribute__((address_space(3))) unsigned int*)l, 16, 0, 0);
}

// tokens fp32 -> bf16 (same [b][pos][ci] layout)
__global__ void cast_tok(const float* __restrict__ t, __hip_bfloat16* __restrict__ o, int n4) {
    for (int i = blockIdx.x * 256 + threadIdx.x; i < n4; i += gridDim.x * 256) {
        float4 v = reinterpret_cast<const float4*>(t)[i];
        union { __hip_bfloat16 h[4]; short4 s; } u;
        u.h[0] = __float2bfloat16(v.x); u.h[1] = __float2bfloat16(v.y);
        u.h[2] = __float2bfloat16(v.z); u.h[3] = __float2bfloat16(v.w);
        reinterpret_cast<short4*>(o)[i] = u.s;
    }
}

// fh_w1/wp_w1 [co][ci][3][3] -> wtb[kk][co(512)][ci] bf16
// Thread per (co,ci): 36B contiguous read, 9 coalesced write streams.
__global__ void build_wtb(const float* __restrict__ fh, const float* __restrict__ wp,
                          __hip_bfloat16* __restrict__ wtb) {
    int t = blockIdx.x * 256 + threadIdx.x;
    if (t >= NCO * CIN) return;
    int co = t / CIN, ci = t % CIN;
    const float* src = (co < HID) ? fh + ((size_t)co * CIN + ci) * 9
                                  : wp + ((size_t)(co - HID) * CIN + ci) * 9;
    #pragma unroll
    for (int kk = 0; kk < 9; ++kk)
        wtb[(size_t)kk * NCO * CIN + t] = __float2bfloat16(src[kk]);
}

// wp_w2 [KOUT][HID][1][1] -> wt2b [KOUTP][HID] bf16 (pad rows zero)
__global__ void cast_wt2b(const float* __restrict__ w, __hip_bfloat16* __restrict__ o) {
    int idx = blockIdx.x * 256 + threadIdx.x;
    if (idx >= KOUTP * HID) return;
    int co = idx / HID;
    o[idx] = (co < KOUT) ? __float2bfloat16(w[idx]) : __hip_bfloat16(0.f);
}

// Implicit-GEMM 3x3 conv via MFMA: M=positions(128/block), N=co(128/block), K=9*768.
// R6: XCD-chunked co-major block swizzle (A-tile reuse in per-XCD L2) +
//     st-style LDS XOR swizzle (both sides: pre-swizzled global src, XOR'd ds_read).
__global__ void conv1_mfma(const __hip_bfloat16* __restrict__ tok,
                           const __hip_bfloat16* __restrict__ wtb,
                           const float* __restrict__ fh_b1, const float* __restrict__ wp_b1,
                           const char* __restrict__ zpage,
                           float* __restrict__ h1f, __hip_bfloat16* __restrict__ h1wb) {
    __shared__ __align__(16) __hip_bfloat16 As[128 * 64];   // [pos][k], XOR-swizzled
    __shared__ __align__(16) __hip_bfloat16 Bs[128 * 64];   // [co][k],  XOR-swizzled
    // --- block swizzle: hw%8 = XCD (round-robin dispatch assumption); give each
    // XCD 88 consecutive logical blocks; logical order = co fastest (4 co-blocks
    // sharing one A pos-tile run adjacent on one XCD -> A L2-hits). Bijective:
    // 704 = 8*88 exactly.
    const int hw      = blockIdx.x;
    const int logical = (hw & 7) * 88 + (hw >> 3);
    const int co0  = (logical & 3) * 128;
    const int pos0 = ((logical >> 2) % 11) * 128;
    const int bb   = logical / 44;
    const int tid  = threadIdx.x;
    const int wv   = tid >> 6, lane = tid & 63;
    const int wr   = wv >> 1,  wc   = wv & 1;

    // staging: chunk c = wv*4+i covers rows 8c..8c+7; lane's LDS slot is
    // (row = c*8 + lane>>3, slot16 = lane&7). XOR swizzle: slot holds logical
    // col16 = slot ^ (row&7) = (lane&7) ^ (lane>>3)  -> fetch that k-offset.
    const int cig = (((lane & 7) ^ (lane >> 3)) * 8);   // k offset (elements)
    int h_i[4], w_i[4]; bool inb[4];
    const char* bsrcb[4];
    char *alds[4], *blds[4];
    #pragma unroll
    for (int i = 0; i < 4; ++i) {
        int c   = wv * 4 + i;
        int row = c * 8 + (lane >> 3);
        int pos = pos0 + row;
        inb[i] = pos < NPOS;
        h_i[i] = pos / NWI;
        w_i[i] = pos % NWI;
        bsrcb[i] = (const char*)wtb + (((size_t)(co0 + row)) * CIN + cig) * 2;
        alds[i]  = (char*)As + c * 1024;
        blds[i]  = (char*)Bs + c * 1024;
    }

    f32x4 acc[4][4] = {};

    // read side: logical col16 = (lane>>4) + 4*s; phys = logical ^ (row&7),
    // row&7 = lane&7. s-term applied as byte-XOR 64 (bits disjoint).
    const char* apx = (const char*)As + ((wr * 64 + (lane & 15)) * 64) * 2
                    + (((lane >> 4) ^ (lane & 7)) * 16);
    const char* bpx = (const char*)Bs + ((wc * 64 + (lane & 15)) * 64) * 2
                    + (((lane >> 4) ^ (lane & 7)) * 16);

    for (int kk = 0; kk < 9; ++kk) {
        const int dh = kk / 3 - 1, dw = kk % 3 - 1;
        const size_t kkoff = (size_t)kk * NCO * CIN * 2;
        const char* asrc[4];
        #pragma unroll
        for (int i = 0; i < 4; ++i) {
            int hh = h_i[i] + dh, ww = w_i[i] + dw;
            bool v = inb[i] && (unsigned)hh < NWI && (unsigned)ww < NWI;
            asrc[i] = v ? (const char*)tok + (((size_t)bb * NPOS + hh * NWI + ww) * CIN + cig) * 2
                        : zpage;
        }
        for (int k0 = 0; k0 < CIN; k0 += 64) {
            const int kb = k0 * 2;
            #pragma unroll
            for (int i = 0; i < 4; ++i) gl_lds16(asrc[i] + kb, alds[i]);
            #pragma unroll
            for (int i = 0; i < 4; ++i) gl_lds16(bsrcb[i] + kkoff + kb, blds[i]);
            __syncthreads();
            #pragma unroll
            for (int s = 0; s < 2; ++s) {
                bf16x8 af[4], bf[4];
                #pragma unroll
                for (int mf = 0; mf < 4; ++mf)
                    af[mf] = *reinterpret_cast<const bf16x8*>(
                        (const void*)((uintptr_t)(apx + mf * 16 * 128) ^ (uintptr_t)(s * 64)));
                #pragma unroll
                for (int nf = 0; nf < 4; ++nf)
                    bf[nf] = *reinterpret_cast<const bf16x8*>(
                        (const void*)((uintptr_t)(bpx + nf * 16 * 128) ^ (uintptr_t)(s * 64)));
                #pragma unroll
                for (int mf = 0; mf < 4; ++mf)
                    #pragma unroll
                    for (int nf = 0; nf < 4; ++nf)
                        acc[mf][nf] = __builtin_amdgcn_mfma_f32_16x16x32_bf16(
                            af[mf], bf[nf], acc[mf][nf], 0, 0, 0);
            }
            __syncthreads();
        }
    }

    // epilogue: C/D mapping (m89): n = lane&15, m = (lane>>4)*4 + r
    const bool  isF   = (co0 < HID);
    const float* bias = isF ? fh_b1 : wp_b1;
    const int cobase  = isF ? co0 : co0 - HID;
    const int nl = lane & 15, mh = (lane >> 4) * 4;
    #pragma unroll
    for (int mf = 0; mf < 4; ++mf) {
        #pragma unroll
        for (int r = 0; r < 4; ++r) {
            int pos = pos0 + wr * 64 + mf * 16 + mh + r;
            if (pos >= NPOS) continue;
            int h = pos / NWI, w = pos % NWI;
            #pragma unroll
            for (int nf = 0; nf < 4; ++nf) {
                int c = cobase + wc * 64 + nf * 16 + nl;
                float v = fmaxf(acc[mf][nf][r] + bias[c], 0.f);
                if (isF)
                    h1f[(((size_t)bb * HID + c) * PADW + h + 1) * PADW + w + 1] = v;
                else
                    h1wb[((size_t)bb * NPOS + pos) * HID + c] = __float2bfloat16(v);
            }
        }
    }
}

// 3x3 conv 256->3 (+bias, xP) -> padded fpad. 32 pos x 8 ci-groups per block.
__global__ __launch_bounds__(256) void conv3_small(const float* __restrict__ h1f,
                                                   const float* __restrict__ w2,
                                                   const float* __restrict__ b2,
                                                   float* __restrict__ fpad) {
    __shared__ float red[8][3][32];
    int tid = threadIdx.x;
    int pl = tid & 31, cg = tid >> 5;
    int idx = blockIdx.x * 32 + pl;
    int bb = 0, pos = 0;
    if (idx < BB * NPOS) { bb = idx / NPOS; pos = idx % NPOS; }
    int h = pos / NWI, w = pos % NWI;
    float a0 = 0.f, a1 = 0.f, a2 = 0.f;
    const float* xb = h1f + ((size_t)bb * HID + cg * 32) * PPAD;
    const float* wb = w2 + cg * 32 * 9;
    for (int cl = 0; cl < 32; ++cl) {
        const float* xr = xb + (size_t)cl * PPAD + h * PADW + w;
        #pragma unroll
        for (int kk = 0; kk < 9; ++kk) {
            float x = xr[(kk / 3) * PADW + (kk % 3)];
            a0 += x * wb[cl * 9 + kk];
            a1 += x * wb[2304 + cl * 9 + kk];
            a2 += x * wb[4608 + cl * 9 + kk];
        }
    }
    red[cg][0][pl] = a0; red[cg][1][pl] = a1; red[cg][2][pl] = a2;
    __syncthreads();
    if (tid < 96) {
        int c = tid >> 5, p2 = tid & 31;
        float s = 0.f;
        #pragma unroll
        for (int q = 0; q < 8; ++q) s += red[q][c][p2];
        int idx2 = blockIdx.x * 32 + p2;
        if (idx2 < BB * NPOS) {
            int b2i = idx2 / NPOS, ps = idx2 % NPOS;
            int hh = ps / NWI, ww = ps % NWI;
            fpad[(((size_t)b2i * 3 + c) * PADW + hh + 1) * PADW + ww + 1] = 14.f * (s + b2[c]);
        }
    }
}

// MFMA 1x1 conv (256->1792) + softmax(9) + neighbor einsum + pixel shuffle + sigmoid.
__global__ __launch_bounds__(256) void wp2_mfma(const __hip_bfloat16* __restrict__ h1wb,
                                                const __hip_bfloat16* __restrict__ wt2b,
                                                const float* __restrict__ b2,
                                                const float* __restrict__ fpad,
                                                float* __restrict__ out) {
    extern __shared__ char smem[];
    __hip_bfloat16* wraw = (__hip_bfloat16*)smem;              // [16][WSTR]
    float* nbr = (float*)(smem + (size_t)16 * WSTR * 2);       // [16][27]
    const int bb = blockIdx.y, pos0 = blockIdx.x * 16;
    const int tid = threadIdx.x, wv = tid >> 6, lane = tid & 63;
    const int nl = lane & 15, g = lane >> 4;

    for (int e = tid; e < 16 * 27; e += 256) {
        int p = e / 27, r = e % 27;
        int c = r / 9, k = r % 9;
        int i = k / 3, j = k % 3;
        int pos = pos0 + p; float v = 0.f;
        if (pos < NPOS) {
            int h = pos / NWI, w = pos % NWI;
            v = fpad[(((size_t)bb * 3 + c) * PADW + h + i) * PADW + w + j];
        }
        nbr[p * 27 + r] = v;
    }

    int posc = pos0 + nl; if (posc >= NPOS) posc = NPOS - 1;
    const __hip_bfloat16* arow = h1wb + ((size_t)bb * NPOS + posc) * HID + g * 8;
    bf16x8 af[8];
    #pragma unroll
    for (int s = 0; s < 8; ++s) af[s] = *reinterpret_cast<const bf16x8*>(arow + s * 32);

    for (int it = 0; it < 7; ++it) {
        const int cob = it * 256 + wv * 64;
        #pragma unroll
        for (int nf = 0; nf < 4; ++nf) {
            const int co = cob + nf * 16 + nl;
            const __hip_bfloat16* brow = wt2b + (size_t)co * HID + g * 8;
            f32x4 a = {0.f, 0.f, 0.f, 0.f};
            #pragma unroll
            for (int s = 0; s < 8; ++s) {
                bf16x8 bf = *reinterpret_cast<const bf16x8*>(brow + s * 32);
                a = __builtin_amdgcn_mfma_f32_16x16x32_bf16(af[s], bf, a, 0, 0, 0);
            }
            float bz = (co < KOUT) ? b2[co] : 0.f;
            #pragma unroll
            for (int r = 0; r < 4; ++r)
                wraw[(g * 4 + r) * WSTR + co] = __float2bfloat16(a[r] + bz);
        }
    }
    __syncthreads();

    for (int t = tid; t < 16 * 196; t += 256) {
        int p = t / 196, pq = t % 196;
        int pos = pos0 + p; if (pos >= NPOS) continue;
        float v[9]; float m = -1e30f;
        #pragma unroll
        for (int k = 0; k < 9; ++k) {
            v[k] = __bfloat162float(wraw[p * WSTR + k * 196 + pq]);
            m = fmaxf(m, v[k]);
        }
        float s = 0.f;
        #pragma unroll
        for (int k = 0; k < 9; ++k) { v[k] = __expf(v[k] - m); s += v[k]; }
        float inv = 1.f / s;
        int h = pos / NWI, w = pos % NWI;
        int pp = pq / PP, qq = pq % PP;
        int Y = h * PP + pp, X = w * PP + qq;
        const float* nb = &nbr[p * 27];
        float u0 = 0.f, u1 = 0.f, u2 = 0.f;
        #pragma unroll
        for (int k = 0; k < 9; ++k) {
            u0 += v[k] * nb[k]; u1 += v[k] * nb[9 + k]; u2 += v[k] * nb[18 + k];
        }
        out[(((size_t)bb * 2 + 0) * HOUT + Y) * HOUT + X] = u0 * inv;
        out[(((size_t)bb * 2 + 1) * HOUT + Y) * HOUT + X] = u1 * inv;
        out[CONF_OFF + ((size_t)bb * HOUT + Y) * HOUT + X] = 1.f / (1.f + __expf(-u2 * inv));
    }
}

extern "C" void kernel_launch(void* const* d_in, const int* in_sizes, int n_in,
                              void* d_out, int out_size, void* d_ws, size_t ws_size,
                              hipStream_t stream) {
    const float* tokens = (const float*)d_in[0];
    const float* fh_w1  = (const float*)d_in[1];
    const float* fh_b1  = (const float*)d_in[2];
    const float* fh_w2  = (const float*)d_in[3];
    const float* fh_b2  = (const float*)d_in[4];
    const float* wp_w1  = (const float*)d_in[5];
    const float* wp_b1  = (const float*)d_in[6];
    const float* wp_w2  = (const float*)d_in[7];
    const float* wp_b2  = (const float*)d_in[8];
    float* out = (float*)d_out;

    char* ws = (char*)d_ws;
    float*           h1f  = (float*)(ws + B_H1F);
    float*           fpad = (float*)(ws + B_FPAD);
    __hip_bfloat16*  h1wb = (__hip_bfloat16*)(ws + B_H1WB);
    __hip_bfloat16*  tokb = (__hip_bfloat16*)(ws + B_TOK);
    __hip_bfloat16*  wtb  = (__hip_bfloat16*)(ws + B_WTB);
    __hip_bfloat16*  wt2b = (__hip_bfloat16*)(ws + B_WT2B);
    const char*      zp   = (const char*)(ws + B_ZERO);

    // zero padded fp32 activation buffers (h1f+fpad) + zero page
    hipMemsetAsync(ws + B_H1F, 0, B_H1WB - B_H1F, stream);
    hipMemsetAsync(ws + B_ZERO, 0, 2048, stream);

    // packing
    cast_tok<<<2048, 256, 0, stream>>>(tokens, tokb, BB * NPOS * CIN / 4);
    build_wtb<<<(NCO * CIN + 255) / 256, 256, 0, stream>>>(fh_w1, wp_w1, wtb);
    cast_wt2b<<<(KOUTP * HID + 255) / 256, 256, 0, stream>>>(wp_w2, wt2b);

    // big conv pair as one MFMA implicit GEMM (1D grid, XCD-chunked swizzle)
    conv1_mfma<<<704, 256, 0, stream>>>(tokb, wtb, fh_b1, wp_b1, zp, h1f, h1wb);

    // flow conv (256->3), scaled by P, into padded fpad
    conv3_small<<<(BB * NPOS + 31) / 32, 256, 0, stream>>>(h1f, fh_w2, fh_b2, fpad);

    // fused MFMA tail
    size_t smem = (size_t)16 * WSTR * 2 + (size_t)16 * 27 * 4;
    wp2_mfma<<<dim3((NPOS + 15) / 16, BB), 256, smem, stream>>>(h1wb, wt2b, wp_b2, fpad, out);
}